// Round 11
// baseline (144.051 us; speedup 1.0000x reference)
//
#include <hip/hip_runtime.h>
#include <hip/hip_bf16.h>

#define B 128
#define N 1024
#define L 512
#define D 64

typedef float f32x4 __attribute__((ext_vector_type(4)));
typedef short bf16x8 __attribute__((ext_vector_type(8)));

// 8 fp32 -> 8 bf16 (RNE) via packed HW cvt
__device__ inline bf16x8 cvt8(float4 f0, float4 f1) {
    union { __hip_bfloat162 h2[4]; bf16x8 v; } u;
    u.h2[0] = __float22bfloat162_rn(make_float2(f0.x, f0.y));
    u.h2[1] = __float22bfloat162_rn(make_float2(f0.z, f0.w));
    u.h2[2] = __float22bfloat162_rn(make_float2(f1.x, f1.y));
    u.h2[3] = __float22bfloat162_rn(make_float2(f1.z, f1.w));
    return u.v;
}

// async global->LDS DMA, 16B per lane; LDS dest = wave-uniform base + lane*16
__device__ __forceinline__ void gload16(const void* g, void* l) {
    __builtin_amdgcn_global_load_lds(
        (const __attribute__((address_space(1))) void*)g,
        (__attribute__((address_space(3))) void*)l, 16, 0, 0);
}

// ============================ bf16-workspace path ============================
// Fused pre-pass: blocks [0,B): mask counts; blocks [B,B+512): I fp32->bf16.
__global__ __launch_bounds__(256) void prep_kernel(
        const float* __restrict__ tmask, const float* __restrict__ imask,
        const float* __restrict__ I,
        int* __restrict__ counts, unsigned short* __restrict__ Ibf) {
    int blk = blockIdx.x, tid = threadIdx.x;
    if (blk < B) {
        int b = blk;
        int w = tid >> 6, lane = tid & 63;
        float ts = 0.f, is = 0.f;
        const float* tm = tmask + (size_t)b * N;
#pragma unroll
        for (int i = 0; i < N / 256; ++i) ts += tm[tid + i * 256];
        const float* im = imask + (size_t)b * L;
#pragma unroll
        for (int i = 0; i < L / 256; ++i) is += im[tid + i * 256];
        for (int off = 32; off; off >>= 1) {
            ts += __shfl_down(ts, off);
            is += __shfl_down(is, off);
        }
        __shared__ float red[8];
        if (lane == 0) { red[w] = ts; red[4 + w] = is; }
        __syncthreads();
        if (tid == 0) counts[b]     = (int)(red[0] + red[1] + red[2] + red[3] + 0.5f);
        if (tid == 1) counts[B + b] = (int)(red[4] + red[5] + red[6] + red[7] + 0.5f);
    } else {
        int t = (blk - B) * 256 + tid;                 // 0..131071
#pragma unroll
        for (int j = 0; j < 4; ++j) {
            size_t ci = (size_t)t + (size_t)j * 131072;
            const float4* p = (const float4*)(I + ci * 8);
            *(bf16x8*)(Ibf + ci * 8) = cvt8(p[0], p[1]);
        }
    }
}

// grid = 1536 blocks (s,b,token-chunk) x 256 thr.
// WAVE-PRIVATE BARRIER-FREE PIPELINE (r10 structure, UNITS BUG FIXED):
// each wave owns 3 private 2KB LDS buffers (16-region chunks) and DMAs for
// itself. A wave's s_waitcnt vmcnt(N) makes its own DMA visible to its own
// ds_read -> NO __syncthreads in the loop, no cross-wave coupling at all.
// LDS 24KB/block + launch_bounds(256,6) -> 6 blocks/CU x 256 CU = 1536 =
// WHOLE GRID resident in one round, 24 independent waves/CU. Depth-2
// prefetch keeps 4-6 x 16B loads/lane continuously in flight -> sustained
// HBM streaming instead of the phase-serial drains that capped r8/r9.
// Ledger (counter cleaned after afrag): prologue stage(0,1) [4 ops]; iter k:
// stage(k+2) [->6]; wait vmcnt(4) => chunk k landed; tail vmcnt(2)/vmcnt(0).
// Chunk buffer layout (2KB = 2 halves x 1024 BYTES, 64 lanes x 16B each):
//   DMA j in {0,1}: src = Ibase + r*D + j*32 + (lane>>4)*8, r = k*16+(lane&15)
//   dst BYTES = j*1024 + lane*16  ->  shorts: buf + j*512 + lane*8
//   (r10 bug: wrote buf + 1024 SHORTS for j=1 = byte 2048 -> next buffer;
//    read expected byte 1024. Fixed: buf + 512 shorts.)
// Read lane(q,c): b_h = (char*)buf + h*1024 + lane*16 -> region c of chunk,
// K-elems h*32+q*8 .. +8 -> pairs afrag[tt][h]. Conflict-free (16B/lane).
__global__ __launch_bounds__(256, 6) void sim_kernel_bf16(
        const float* __restrict__ T, const unsigned short* __restrict__ Ibf,
        const int* __restrict__ counts,
        const int* __restrict__ Iimp, const int* __restrict__ Simp,
        float* __restrict__ partials) {
    int blk = blockIdx.x;          // 0..1535
    int chunk = blk & 3;
    int bs = blk >> 2;
    int b = bs & (B - 1);
    int s = bs >> 7;
    int Tb = b, Ib = b;
    if (s == 1) Tb = Simp[b];
    else if (s == 2) Ib = Iimp[b];

    int tid = threadIdx.x;
    int w = tid >> 6;
    int lane = tid & 63;
    int q = lane >> 4;
    int c = lane & 15;

    int ntok = counts[Tb];         // block-uniform
    int nreg = counts[B + Ib];

    int tok0 = chunk << 8;
    if (chunk != 0 && tok0 >= ntok) {      // ntok >= 256: chunk 0 never exits
        if (tid == 0) partials[blk] = 0.f;
        return;
    }

    __shared__ unsigned short ldsI[4][3][1024];  // per-wave 3 x 2KB buffers
    __shared__ float red[4];

    // ---- A fragments first; consume via cvt, then clean the vmem counter ----
    int wt0 = tok0 + w * 64;
    bf16x8 afrag[4][2];
#pragma unroll
    for (int tt = 0; tt < 4; ++tt) {
        const float* trow = T + ((size_t)Tb * N + wt0 + tt * 16 + c) * D;
#pragma unroll
        for (int h = 0; h < 2; ++h) {
            const float4* p = (const float4*)(trow + h * 32 + q * 8);
            afrag[tt][h] = cvt8(p[0], p[1]);
        }
    }
    asm volatile("s_waitcnt vmcnt(0)" ::: "memory");   // counter = DMA only below

    float mx[4][4];
#pragma unroll
    for (int tt = 0; tt < 4; ++tt)
#pragma unroll
        for (int i = 0; i < 4; ++i) mx[tt][i] = -3.0e38f;

    const unsigned short* Ibase = Ibf + (size_t)Ib * L * D;
    int nch = (nreg + 15) >> 4;                  // 8..32 16-region chunks
    int nregm1 = nreg - 1;
    int srcoff = (lane >> 4) * 8;                // elems q*8

    auto stage = [&](int k) {
        unsigned short* buf = &ldsI[w][k % 3][0];
        int r = (k << 4) + c;
        if (r > nregm1) r = nregm1;              // duplicate valid row: max-neutral
        const unsigned short* src = Ibase + (size_t)r * D + srcoff;
        gload16(src,      buf + (size_t)lane * 8);         // j=0 -> bytes [0,1024)
        gload16(src + 32, buf + 512 + (size_t)lane * 8);   // j=1 -> bytes [1024,2048)
    };

    stage(0);
    stage(1);

    for (int k = 0; k < nch; ++k) {
        if (k + 2 < nch) {
            stage(k + 2);                        // 6 outstanding after issue
            asm volatile("s_waitcnt vmcnt(4)" ::: "memory");   // chunk k landed
        } else if (k + 1 < nch) {
            asm volatile("s_waitcnt vmcnt(2)" ::: "memory");
        } else {
            asm volatile("s_waitcnt vmcnt(0)" ::: "memory");
        }

        const char* base = (const char*)&ldsI[w][k % 3][0] + (size_t)lane * 16;
        bf16x8 b0 = *(const bf16x8*)(base);
        bf16x8 b1 = *(const bf16x8*)(base + 1024);
#pragma unroll
        for (int tt = 0; tt < 4; ++tt) {
            f32x4 acc = {0.f, 0.f, 0.f, 0.f};
            acc = __builtin_amdgcn_mfma_f32_16x16x32_bf16(afrag[tt][0], b0, acc, 0, 0, 0);
            acc = __builtin_amdgcn_mfma_f32_16x16x32_bf16(afrag[tt][1], b1, acc, 0, 0, 0);
#pragma unroll
            for (int i = 0; i < 4; ++i) mx[tt][i] = fmaxf(mx[tt][i], acc[i]);
        }
    }

    // ---- cross-lane max over 16 region-cols ----
#pragma unroll
    for (int m = 1; m < 16; m <<= 1) {
#pragma unroll
        for (int tt = 0; tt < 4; ++tt)
#pragma unroll
            for (int i = 0; i < 4; ++i)
                mx[tt][i] = fmaxf(mx[tt][i], __shfl_xor(mx[tt][i], m));
    }

    // ---- masked token sum (C layout: row = q*4 + i) ----
    float bsum = 0.f;
    if (c == 0) {
#pragma unroll
        for (int tt = 0; tt < 4; ++tt)
#pragma unroll
            for (int i = 0; i < 4; ++i) {
                int row = wt0 + tt * 16 + q * 4 + i;
                if (row < ntok) bsum += mx[tt][i];
            }
    }
    for (int off = 32; off; off >>= 1) bsum += __shfl_down(bsum, off);
    if (lane == 0) red[w] = bsum;
    __syncthreads();                             // only barrier in the kernel
    if (tid == 0)
        partials[blk] = (red[0] + red[1] + red[2] + red[3]) / (float)ntok;
}

// ===================== fallback path (tiny workspace, r3) =====================
__global__ __launch_bounds__(256) void count_kernel(
        const float* __restrict__ tmask, const float* __restrict__ imask,
        int* __restrict__ counts) {
    int b = blockIdx.x, tid = threadIdx.x;
    int w = tid >> 6, lane = tid & 63;
    float ts = 0.f, is = 0.f;
    const float* tm = tmask + (size_t)b * N;
#pragma unroll
    for (int i = 0; i < N / 256; ++i) ts += tm[tid + i * 256];
    const float* im = imask + (size_t)b * L;
#pragma unroll
    for (int i = 0; i < L / 256; ++i) is += im[tid + i * 256];
    for (int off = 32; off; off >>= 1) {
        ts += __shfl_down(ts, off);
        is += __shfl_down(is, off);
    }
    __shared__ float red[8];
    if (lane == 0) { red[w] = ts; red[4 + w] = is; }
    __syncthreads();
    if (tid == 0) counts[b]     = (int)(red[0] + red[1] + red[2] + red[3] + 0.5f);
    if (tid == 1) counts[B + b] = (int)(red[4] + red[5] + red[6] + red[7] + 0.5f);
}

// verbatim round-3 sim kernel (passed): fp32 DMA staging, 3x16KB LDS
__global__ __launch_bounds__(256, 3) void sim_kernel_f32(
        const float* __restrict__ T, const float* __restrict__ I,
        const int* __restrict__ counts,
        const int* __restrict__ Iimp, const int* __restrict__ Simp,
        float* __restrict__ partials) {
    int blk = blockIdx.x;
    int chunk = blk & 3;
    int bs = blk >> 2;
    int b = bs & (B - 1);
    int s = bs >> 7;
    int Tb = b, Ib = b;
    if (s == 1) Tb = Simp[b];
    else if (s == 2) Ib = Iimp[b];

    int tid = threadIdx.x;
    int w = tid >> 6;
    int lane = tid & 63;
    int q = lane >> 4;
    int c = lane & 15;

    int ntok = counts[Tb];
    int nreg = counts[B + Ib];

    int tok0 = chunk << 8;
    if (chunk != 0 && tok0 >= ntok) {
        if (tid == 0) partials[blk] = 0.f;
        return;
    }

    __shared__ float ldsI[3][4096];
    __shared__ float red[4];

    int wt0 = tok0 + w * 64;
    bf16x8 afrag[4][2];
#pragma unroll
    for (int tt = 0; tt < 4; ++tt) {
        const float* trow = T + ((size_t)Tb * N + wt0 + tt * 16 + c) * D;
#pragma unroll
        for (int h = 0; h < 2; ++h) {
            const float4* p = (const float4*)(trow + h * 32 + q * 8);
            afrag[tt][h] = cvt8(p[0], p[1]);
        }
    }

    float mx[4][4];
#pragma unroll
    for (int tt = 0; tt < 4; ++tt)
#pragma unroll
        for (int i = 0; i < 4; ++i) mx[tt][i] = -3.0e38f;

    int rloc[4], foff[4];
#pragma unroll
    for (int j = 0; j < 4; ++j) {
        int ci = tid + j * 256;
        int fh = ci >> 7, idx = ci & 127, half = idx >> 6, ln2 = idx & 63;
        rloc[j] = (fh >> 1) * 16 + (ln2 & 15);
        foff[j] = (fh & 1) * 32 + (ln2 >> 4) * 8 + half * 4;
    }
    const float* Ibase = I + (size_t)Ib * L * D;
    int nchunks = (nreg + 63) >> 6;
    int nregm1 = nreg - 1;

    auto stage = [&](int k) {
        float* buf = &ldsI[k % 3][0];
        int rbase = k << 6;
#pragma unroll
        for (int j = 0; j < 4; ++j) {
            int r = rbase + rloc[j];
            if (r > nregm1) r = nregm1;
            gload16(Ibase + (size_t)r * D + foff[j], buf + (tid + j * 256) * 4);
        }
    };

    asm volatile("s_waitcnt vmcnt(0)" ::: "memory");
    stage(0);
    stage(1);
    asm volatile("s_waitcnt vmcnt(4)" ::: "memory");
    __builtin_amdgcn_s_barrier();

    for (int k = 0; k < nchunks; ++k) {
        if (k + 2 < nchunks) stage(k + 2);

        const char* base = (const char*)&ldsI[k % 3][0] + (size_t)lane * 16;
#pragma unroll
        for (int rt = 0; rt < 4; ++rt) {
            float4 e0 = *(const float4*)(base + (rt * 2 + 0) * 2048);
            float4 e1 = *(const float4*)(base + (rt * 2 + 0) * 2048 + 1024);
            float4 e2 = *(const float4*)(base + (rt * 2 + 1) * 2048);
            float4 e3 = *(const float4*)(base + (rt * 2 + 1) * 2048 + 1024);
            bf16x8 b0 = cvt8(e0, e1);
            bf16x8 b1 = cvt8(e2, e3);
#pragma unroll
            for (int tt = 0; tt < 4; ++tt) {
                f32x4 acc = {0.f, 0.f, 0.f, 0.f};
                acc = __builtin_amdgcn_mfma_f32_16x16x32_bf16(afrag[tt][0], b0, acc, 0, 0, 0);
                acc = __builtin_amdgcn_mfma_f32_16x16x32_bf16(afrag[tt][1], b1, acc, 0, 0, 0);
#pragma unroll
                for (int i = 0; i < 4; ++i) mx[tt][i] = fmaxf(mx[tt][i], acc[i]);
            }
        }

        if (k + 1 < nchunks) {
            if (k + 2 < nchunks)
                asm volatile("s_waitcnt vmcnt(4) lgkmcnt(0)" ::: "memory");
            else
                asm volatile("s_waitcnt vmcnt(0) lgkmcnt(0)" ::: "memory");
            __builtin_amdgcn_s_barrier();
        }
    }

#pragma unroll
    for (int m = 1; m < 16; m <<= 1) {
#pragma unroll
        for (int tt = 0; tt < 4; ++tt)
#pragma unroll
            for (int i = 0; i < 4; ++i)
                mx[tt][i] = fmaxf(mx[tt][i], __shfl_xor(mx[tt][i], m));
    }

    float bsum = 0.f;
    if (c == 0) {
#pragma unroll
        for (int tt = 0; tt < 4; ++tt)
#pragma unroll
            for (int i = 0; i < 4; ++i) {
                int row = wt0 + tt * 16 + q * 4 + i;
                if (row < ntok) bsum += mx[tt][i];
            }
    }
    for (int off = 32; off; off >>= 1) bsum += __shfl_down(bsum, off);
    if (lane == 0) red[w] = bsum;
    __syncthreads();
    if (tid == 0)
        partials[blk] = (red[0] + red[1] + red[2] + red[3]) / (float)ntok;
}

// 1 block x 384 threads: fold 1536 partials -> 384 sims -> hinge -> loss
__global__ void loss_kernel(const float* __restrict__ partials,
                            float* __restrict__ out) {
    int tid = threadIdx.x;  // 0..383
    __shared__ float simsL[384];
    __shared__ float w6[6];
    const float4* p4 = (const float4*)partials;
    float4 v = p4[tid];
    simsL[tid] = v.x + v.y + v.z + v.w;
    __syncthreads();
    float per = 0.f;
    if (tid < B) {
        float anc  = simsL[tid];
        float simp = simsL[B + tid];
        float iimp = simsL[2 * B + tid];
        per = fmaxf(1.f + iimp - anc, 0.f) + fmaxf(1.f + simp - anc, 0.f);
    }
    for (int off = 32; off; off >>= 1) per += __shfl_down(per, off);
    if ((tid & 63) == 0) w6[tid >> 6] = per;
    __syncthreads();
    if (tid == 0)
        out[0] = (w6[0] + w6[1] + w6[2] + w6[3] + w6[4] + w6[5]) / (float)B;
}

extern "C" void kernel_launch(void* const* d_in, const int* in_sizes, int n_in,
                              void* d_out, int out_size, void* d_ws, size_t ws_size,
                              hipStream_t stream) {
    const float* T     = (const float*)d_in[0];
    const float* I     = (const float*)d_in[1];
    const float* tmask = (const float*)d_in[2];
    const float* imask = (const float*)d_in[3];
    const int*   Iimp  = (const int*)d_in[4];
    const int*   Simp  = (const int*)d_in[5];
    // ws: counts[256] ints @0 | partials[1536] f32 @1024 | Ibf bf16 @8192
    int*   counts   = (int*)d_ws;
    float* partials = (float*)((char*)d_ws + 1024);
    size_t need_bf16 = 8192 + (size_t)B * L * D * sizeof(unsigned short);

    if (ws_size >= need_bf16) {
        unsigned short* Ibf = (unsigned short*)((char*)d_ws + 8192);
        prep_kernel<<<B + 512, 256, 0, stream>>>(tmask, imask, I, counts, Ibf);
        sim_kernel_bf16<<<3 * B * 4, 256, 0, stream>>>(T, Ibf, counts, Iimp, Simp, partials);
    } else {
        count_kernel<<<B, 256, 0, stream>>>(tmask, imask, counts);
        sim_kernel_f32<<<3 * B * 4, 256, 0, stream>>>(T, I, counts, Iimp, Simp, partials);
    }
    loss_kernel<<<1, 384, 0, stream>>>(partials, (float*)d_out);
}